// Round 1
// baseline (1370.056 us; speedup 1.0000x reference)
//
#include <hip/hip_runtime.h>
#include <math.h>

// Sizes: B=32, C_IN=3, H=W=128, MID=64
// h0: (32,64,128,128) raw conv0 out
// h1: (32,64,62,62)   raw pool(conv1(bnrelu(h0)))
// h2: (32,64,29,29)
// h3: (32,64,13,13)
// stats st: 4 layers x 64 ch x {sum,sumsq}
// sb: 4 layers x 64 ch x {scale,bias}

// ---------------- conv0: 1x1 conv 3->64 ----------------
__global__ __launch_bounds__(256) void k_conv0(const float* __restrict__ x,
                                               const float* __restrict__ w0,
                                               float* __restrict__ h0) {
  int idx = blockIdx.x * 256 + threadIdx.x;   // ((b*64+c)*16384 + p)
  int p  = idx & 16383;
  int bc = idx >> 14;
  int c = bc & 63, b = bc >> 6;
  const float* xb = x + (size_t)b * 3 * 16384 + p;
  float v = xb[0]     * w0[c*3+0]
          + xb[16384] * w0[c*3+1]
          + xb[32768] * w0[c*3+2];
  h0[idx] = v;
}

// ---------------- per-channel sum/sumsq ----------------
__global__ __launch_bounds__(256) void k_stats(const float* __restrict__ h,
                                               float* __restrict__ st, int S) {
  int c = blockIdx.x & 63, b = blockIdx.x >> 6;
  const float* base = h + (size_t)(b * 64 + c) * S;
  float s = 0.f, s2 = 0.f;
  for (int i = threadIdx.x; i < S; i += 256) {
    float v = base[i]; s += v; s2 += v * v;
  }
  __shared__ float r1[256], r2[256];
  r1[threadIdx.x] = s; r2[threadIdx.x] = s2;
  __syncthreads();
  for (int str = 128; str > 0; str >>= 1) {
    if (threadIdx.x < str) {
      r1[threadIdx.x] += r1[threadIdx.x + str];
      r2[threadIdx.x] += r2[threadIdx.x + str];
    }
    __syncthreads();
  }
  if (threadIdx.x == 0) {
    atomicAdd(&st[2*c],   r1[0]);
    atomicAdd(&st[2*c+1], r2[0]);
  }
}

__global__ void k_finalize(const float* __restrict__ st,
                           const float* __restrict__ gamma,
                           const float* __restrict__ beta,
                           float* __restrict__ sb, int layer, float invN) {
  int t = threadIdx.x;
  if (t >= 64) return;
  float m   = st[2*t] * invN;
  float var = st[2*t+1] * invN - m * m;
  float sc  = gamma[layer*64+t] / sqrtf(var + 1e-5f);
  sb[2*t]   = sc;
  sb[2*t+1] = beta[layer*64+t] - m * sc;
}

// ------------- fused bnrelu(in) -> 3x3 conv -> 3x3/s2 maxpool -------------
// block: (b, cog of 16 out-ch, strip of PRB pooled rows x full pooled width)
template<int IN, int POOLW, int PRB>
__global__ __launch_bounds__(256) void k_convpool(const float* __restrict__ in,
                                                  const float* __restrict__ w,
                                                  const float* __restrict__ sb,
                                                  float* __restrict__ out) {
  constexpr int CRB    = 2*PRB + 1;        // conv rows per strip
  constexpr int CW     = 2*POOLW + 1;      // conv cols actually used
  constexpr int CPW    = (CW + 15) / 16;   // conv cols per worker
  constexpr int INROWS = CRB + 2;
  constexpr int ITW    = 16*CPW + 2;       // padded input tile width
  constexpr int CTW    = 16*CPW + 1;       // padded conv tile width
  constexpr int NT     = (POOLW + PRB - 1) / PRB;

  __shared__ float itile[INROWS * ITW];
  __shared__ float wtile[144];
  __shared__ float ctile[16 * CRB * CTW];

  int bid = blockIdx.x;
  int t   = bid % NT;
  int cog = (bid / NT) & 3;
  int b   = bid / (NT * 4);
  int pr0 = t * PRB;
  int tid = threadIdx.x;
  int co  = tid & 15, wkr = tid >> 4, c0 = wkr * CPW;

  float acc[CRB][CPW];
  #pragma unroll
  for (int r = 0; r < CRB; ++r)
    #pragma unroll
    for (int j = 0; j < CPW; ++j) acc[r][j] = 0.f;

  for (int ci = 0; ci < 64; ++ci) {
    __syncthreads();
    const float* ip = in + (size_t)(b * 64 + ci) * (IN * IN);
    float sc = sb[2*ci], bi = sb[2*ci+1];
    for (int li = tid; li < INROWS * IN; li += 256) {
      int ir = li / IN, cc = li - ir * IN;
      int grow = 2 * pr0 + ir;
      float v = 0.f;
      if (grow < IN) v = fmaxf(ip[grow * IN + cc] * sc + bi, 0.f);
      itile[ir * ITW + cc] = v;
    }
    if (tid < 144)
      wtile[tid] = w[((cog*16 + tid/9) * 64 + ci) * 9 + (tid % 9)];
    __syncthreads();

    float wr[9];
    #pragma unroll
    for (int k = 0; k < 9; ++k) wr[k] = wtile[co*9 + k];

    #pragma unroll
    for (int ir = 0; ir < INROWS; ++ir) {
      float seg[CPW + 2];
      #pragma unroll
      for (int j = 0; j < CPW + 2; ++j) seg[j] = itile[ir * ITW + c0 + j];
      #pragma unroll
      for (int dr = 0; dr < 3; ++dr) {
        int r = ir - dr;
        if (r >= 0 && r < CRB) {
          #pragma unroll
          for (int j = 0; j < CPW; ++j) {
            acc[r][j] = fmaf(seg[j+0], wr[dr*3+0], acc[r][j]);
            acc[r][j] = fmaf(seg[j+1], wr[dr*3+1], acc[r][j]);
            acc[r][j] = fmaf(seg[j+2], wr[dr*3+2], acc[r][j]);
          }
        }
      }
    }
  }

  __syncthreads();
  #pragma unroll
  for (int r = 0; r < CRB; ++r)
    #pragma unroll
    for (int j = 0; j < CPW; ++j)
      ctile[(co * CRB + r) * CTW + c0 + j] = acc[r][j];
  __syncthreads();

  // pooling: remap so lanes 0..15 share a channel -> coalesced stores
  int co2 = tid >> 4, pw2 = tid & 15;
  for (int pr = 0; pr < PRB; ++pr) {
    if (pr0 + pr >= POOLW) break;
    for (int pc = pw2; pc < POOLW; pc += 16) {
      float m = -INFINITY;
      #pragma unroll
      for (int dr = 0; dr < 3; ++dr)
        #pragma unroll
        for (int dc = 0; dc < 3; ++dc)
          m = fmaxf(m, ctile[(co2 * CRB + 2*pr + dr) * CTW + 2*pc + dc]);
      out[((size_t)(b * 64 + cog * 16 + co2) * POOLW + (pr0 + pr)) * POOLW + pc] = m;
    }
  }
}

// ---------------- theta = bnrelu(h3_flat) @ W_reg.T + b_reg ----------------
__global__ __launch_bounds__(256) void k_theta(const float* __restrict__ h3,
                                               const float* __restrict__ sb3,
                                               const float* __restrict__ Wreg,
                                               const float* __restrict__ breg,
                                               float* __restrict__ theta_raw) {
  int b = blockIdx.x, tid = threadIdx.x;
  float acc[6] = {0.f, 0.f, 0.f, 0.f, 0.f, 0.f};
  const float* hb = h3 + (size_t)b * 10816;
  for (int i = tid; i < 10816; i += 256) {
    int c = i / 169;
    float f = fmaxf(hb[i] * sb3[2*c] + sb3[2*c+1], 0.f);
    #pragma unroll
    for (int j = 0; j < 6; ++j) acc[j] += f * Wreg[j * 10816 + i];
  }
  __shared__ float red[6][256];
  #pragma unroll
  for (int j = 0; j < 6; ++j) red[j][tid] = acc[j];
  __syncthreads();
  for (int s = 128; s > 0; s >>= 1) {
    if (tid < s) {
      #pragma unroll
      for (int j = 0; j < 6; ++j) red[j][tid] += red[j][tid + s];
    }
    __syncthreads();
  }
  if (tid < 6) theta_raw[b * 6 + tid] = red[tid][0] + breg[tid];
}

// ---------------- sequential spectral normalization scan ----------------
__global__ void k_spectral(const float* __restrict__ theta_raw,
                           const float* __restrict__ u0v,
                           const float* __restrict__ v0v,
                           float* __restrict__ theta) {
  if (threadIdx.x != 0 || blockIdx.x != 0) return;
  float ua = u0v[0], ub = u0v[1];
  float va = v0v[0], vb = v0v[1], vc = v0v[2];
  for (int n = 0; n < 32; ++n) {
    float W[6];
    #pragma unroll
    for (int k = 0; k < 6; ++k) W[k] = theta_raw[n * 6 + k];
    #pragma unroll
    for (int it = 0; it < 4; ++it) {
      float t0 = W[0]*ua + W[3]*ub;
      float t1 = W[1]*ua + W[4]*ub;
      float t2 = W[2]*ua + W[5]*ub;
      float nv = fmaxf(sqrtf(t0*t0 + t1*t1 + t2*t2), 1e-12f);
      va = t0/nv; vb = t1/nv; vc = t2/nv;
      float s0 = W[0]*va + W[1]*vb + W[2]*vc;
      float s1 = W[3]*va + W[4]*vb + W[5]*vc;
      float nu = fmaxf(sqrtf(s0*s0 + s1*s1), 1e-12f);
      ua = s0/nu; ub = s1/nu;
    }
    float s0 = W[0]*va + W[1]*vb + W[2]*vc;
    float s1 = W[3]*va + W[4]*vb + W[5]*vc;
    float sigma = ua*s0 + ub*s1;
    #pragma unroll
    for (int k = 0; k < 6; ++k) theta[n * 6 + k] = W[k] / sigma;
  }
}

// ---------------- affine grid + reflection bilinear sample ----------------
__global__ __launch_bounds__(256) void k_sample(const float* __restrict__ x,
                                                const float* __restrict__ theta,
                                                float* __restrict__ out) {
  int idx = blockIdx.x * 256 + threadIdx.x;   // 32*128*128
  int b = idx >> 14, p = idx & 16383;
  int hh = p >> 7, ww = p & 127;
  const float* th = theta + b * 6;
  float xs = (2*ww + 1) * (1.f/128.f) - 1.f;
  float ys = (2*hh + 1) * (1.f/128.f) - 1.f;
  float gx = th[0]*xs + th[1]*ys + th[2];
  float gy = th[3]*xs + th[4]*ys + th[5];
  float ix = ((gx + 1.f) * 128.f - 1.f) * 0.5f;
  float iy = ((gy + 1.f) * 128.f - 1.f) * 0.5f;

  // reflection, lo=-0.5, span=128, then clip [0,127]
  float r;
  r  = fmodf(fabsf(ix + 0.5f), 256.f);
  ix = ((r > 128.f) ? 256.f - r : r) - 0.5f;
  ix = fminf(fmaxf(ix, 0.f), 127.f);
  r  = fmodf(fabsf(iy + 0.5f), 256.f);
  iy = ((r > 128.f) ? 256.f - r : r) - 0.5f;
  iy = fminf(fmaxf(iy, 0.f), 127.f);

  float x0f = floorf(ix), y0f = floorf(iy);
  float wx = ix - x0f, wy = iy - y0f;
  int x0 = (int)x0f; x0 = min(max(x0, 0), 127); int x1 = min(x0 + 1, 127);
  int y0 = (int)y0f; y0 = min(max(y0, 0), 127); int y1 = min(y0 + 1, 127);
  float w00 = (1.f-wx)*(1.f-wy), w10 = wx*(1.f-wy);
  float w01 = (1.f-wx)*wy,       w11 = wx*wy;

  #pragma unroll
  for (int ch = 0; ch < 3; ++ch) {
    const float* xb = x + ((size_t)(b*3 + ch)) * 16384;
    float v = xb[y0*128 + x0]*w00 + xb[y0*128 + x1]*w10
            + xb[y1*128 + x0]*w01 + xb[y1*128 + x1]*w11;
    out[((size_t)(b*3 + ch)) * 16384 + p] = v;
  }
}

__global__ void k_zero(float* p, int n) {
  int i = blockIdx.x * 256 + threadIdx.x;
  if (i < n) p[i] = 0.f;
}

extern "C" void kernel_launch(void* const* d_in, const int* in_sizes, int n_in,
                              void* d_out, int out_size, void* d_ws, size_t ws_size,
                              hipStream_t stream) {
  const float* x     = (const float*)d_in[0];
  const float* w0    = (const float*)d_in[1];
  const float* w1    = (const float*)d_in[2];
  const float* w2    = (const float*)d_in[3];
  const float* w3    = (const float*)d_in[4];
  const float* gamma = (const float*)d_in[5];
  const float* beta  = (const float*)d_in[6];
  const float* Wreg  = (const float*)d_in[7];
  const float* breg  = (const float*)d_in[8];
  const float* u0v   = (const float*)d_in[9];
  const float* v0v   = (const float*)d_in[10];
  float* out = (float*)d_out;

  float* ws   = (float*)d_ws;
  float* h0   = ws;                    // 33554432
  float* h1   = h0 + 33554432;         // 7872512
  float* h2   = h1 + 7872512;          // 1722368
  float* h3   = h2 + 1722368;          // 346112
  float* st   = h3 + 346112;           // 512 (4 layers x 64 x 2)
  float* sb   = st + 512;              // 512
  float* traw = sb + 512;              // 192
  float* tfin = traw + 192;            // 192

  k_zero<<<2, 256, 0, stream>>>(st, 512);
  k_conv0<<<131072, 256, 0, stream>>>(x, w0, h0);

  k_stats<<<2048, 256, 0, stream>>>(h0, st + 0, 16384);
  k_finalize<<<1, 64, 0, stream>>>(st + 0, gamma, beta, sb + 0, 0, 1.f/524288.f);
  k_convpool<128, 62, 2><<<32*4*31, 256, 0, stream>>>(h0, w1, sb + 0, h1);

  k_stats<<<2048, 256, 0, stream>>>(h1, st + 128, 3844);
  k_finalize<<<1, 64, 0, stream>>>(st + 128, gamma, beta, sb + 128, 1, 1.f/123008.f);
  k_convpool<62, 29, 2><<<32*4*15, 256, 0, stream>>>(h1, w2, sb + 128, h2);

  k_stats<<<2048, 256, 0, stream>>>(h2, st + 256, 841);
  k_finalize<<<1, 64, 0, stream>>>(st + 256, gamma, beta, sb + 256, 2, 1.f/26912.f);
  k_convpool<29, 13, 4><<<32*4*4, 256, 0, stream>>>(h2, w3, sb + 256, h3);

  k_stats<<<2048, 256, 0, stream>>>(h3, st + 384, 169);
  k_finalize<<<1, 64, 0, stream>>>(st + 384, gamma, beta, sb + 384, 3, 1.f/5408.f);

  k_theta<<<32, 256, 0, stream>>>(h3, sb + 384, Wreg, breg, traw);
  k_spectral<<<1, 64, 0, stream>>>(traw, u0v, v0v, tfin);
  k_sample<<<2048, 256, 0, stream>>>(x, tfin, out);
}

// Round 3
// 1235.535 us; speedup vs baseline: 1.1089x; 1.1089x over previous
//
#include <hip/hip_runtime.h>
#include <math.h>

// B=32, C_IN=3, H=W=128, MID=64
// Pipeline: [analytic BN0] -> fused conv0+bn0+conv1+pool1 -> bn1 stats ->
//           convpool2 -> bn2 stats -> convpool3 -> bn3 stats -> theta GEMM ->
//           sequential spectral norm -> affine grid + reflection bilinear sample.
// h0 (32,64,128,128) is NEVER materialized: BN0 stats are derived analytically
// from the 3x3 second-moment matrix of x (h0 = w0 . x is linear per-pixel).

// ---------------- x channel stats (for analytic BN0) ----------------
__global__ __launch_bounds__(256) void k_xstats(const float* __restrict__ x,
                                                float* __restrict__ xst) {
  // xst[0..2] = sum x_c ; xst[3..8] = sum of products (00,01,02,11,12,22)
  int g0 = blockIdx.x * 256 + threadIdx.x;
  float a[9] = {0,0,0,0,0,0,0,0,0};
  for (int g = g0; g < 524288; g += 1024 * 256) {
    int b = g >> 14, p = g & 16383;
    const float* xb = x + (size_t)b * 49152 + p;
    float x0 = xb[0], x1 = xb[16384], x2 = xb[32768];
    a[0] += x0; a[1] += x1; a[2] += x2;
    a[3] += x0 * x0; a[4] += x0 * x1; a[5] += x0 * x2;
    a[6] += x1 * x1; a[7] += x1 * x2; a[8] += x2 * x2;
  }
  __shared__ float red[256];
  for (int k = 0; k < 9; ++k) {
    red[threadIdx.x] = a[k];
    __syncthreads();
    for (int s = 128; s > 0; s >>= 1) {
      if (threadIdx.x < s) red[threadIdx.x] += red[threadIdx.x + s];
      __syncthreads();
    }
    if (threadIdx.x == 0) atomicAdd(&xst[k], red[0]);
    __syncthreads();
  }
}

__global__ void k_bn0(const float* __restrict__ xst, const float* __restrict__ w0,
                      const float* __restrict__ gamma, const float* __restrict__ beta,
                      float* __restrict__ sb0) {
  int c = threadIdx.x;
  if (c >= 64) return;
  const float invN = 1.f / 524288.f;
  float mu0 = xst[0] * invN, mu1 = xst[1] * invN, mu2 = xst[2] * invN;
  float M00 = xst[3] * invN, M01 = xst[4] * invN, M02 = xst[5] * invN;
  float M11 = xst[6] * invN, M12 = xst[7] * invN, M22 = xst[8] * invN;
  float wa = w0[c * 3], wb = w0[c * 3 + 1], wc = w0[c * 3 + 2];
  float m  = wa * mu0 + wb * mu1 + wc * mu2;
  float e2 = wa * wa * M00 + wb * wb * M11 + wc * wc * M22
           + 2.f * (wa * wb * M01 + wa * wc * M02 + wb * wc * M12);
  float var = e2 - m * m;
  float sc = gamma[c] / sqrtf(var + 1e-5f);
  sb0[2 * c] = sc;
  sb0[2 * c + 1] = beta[c] - m * sc;
}

// ---------------- per-channel sum/sumsq over (B,HW) ----------------
__global__ __launch_bounds__(256) void k_stats(const float* __restrict__ h,
                                               float* __restrict__ st, int S) {
  int c = blockIdx.x & 63, b = blockIdx.x >> 6;
  const float* base = h + (size_t)(b * 64 + c) * S;
  float s = 0.f, s2 = 0.f;
  for (int i = threadIdx.x; i < S; i += 256) {
    float v = base[i]; s += v; s2 += v * v;
  }
  __shared__ float r1[256], r2[256];
  r1[threadIdx.x] = s; r2[threadIdx.x] = s2;
  __syncthreads();
  for (int str = 128; str > 0; str >>= 1) {
    if (threadIdx.x < str) {
      r1[threadIdx.x] += r1[threadIdx.x + str];
      r2[threadIdx.x] += r2[threadIdx.x + str];
    }
    __syncthreads();
  }
  if (threadIdx.x == 0) {
    atomicAdd(&st[2 * c],     r1[0]);
    atomicAdd(&st[2 * c + 1], r2[0]);
  }
}

__global__ void k_finalize(const float* __restrict__ st,
                           const float* __restrict__ gamma,
                           const float* __restrict__ beta,
                           float* __restrict__ sb, int layer, float invN) {
  int t = threadIdx.x;
  if (t >= 64) return;
  float m   = st[2 * t] * invN;
  float var = st[2 * t + 1] * invN - m * m;
  float sc  = gamma[layer * 64 + t] / sqrtf(var + 1e-5f);
  sb[2 * t]     = sc;
  sb[2 * t + 1] = beta[layer * 64 + t] - m * sc;
}

// ------- layer1 fused: bnrelu(w0.x) on the fly -> 3x3 conv -> pool -------
__global__ __launch_bounds__(256) void k_convpool1(const float* __restrict__ x,
                                                   const float* __restrict__ w0,
                                                   const float* __restrict__ w1,
                                                   const float* __restrict__ sb0,
                                                   float* __restrict__ out) {
  constexpr int POOLW = 62, PRB = 2, CRB = 5, INROWS = 7;
  constexpr int ITW = 132, CTW = 129, NT = 31, CPW = 8;

  __shared__ __align__(16) float itile[INROWS * ITW];   // 924 f
  __shared__ float wtile[144];
  __shared__ __align__(16) float parea[8 * CRB * CTW];  // 5160 f; aliases xtile
  float* xtile = parea;                                 // 3*7*132 = 2772 <= 5160

  int bid = blockIdx.x;
  int t   = bid % NT;
  int cog = (bid / NT) & 3;
  int b   = bid / (NT * 4);
  int pr0 = t * PRB;
  int tid = threadIdx.x;
  int co  = tid & 15, wkr = tid >> 4, c0 = wkr * CPW;

  // stage x rows (3 ch x 7 rows x 128) once; all rows valid (pr0<=60 -> <=126)
  for (int li = tid; li < 2688; li += 256) {
    int ch = li / 896, rem = li - ch * 896;
    int ir = rem >> 7, cc = rem & 127;
    xtile[(ch * 7 + ir) * ITW + cc] =
        x[((size_t)(b * 3 + ch) << 14) + (2 * pr0 + ir) * 128 + cc];
  }

  float acc[CRB][CPW];
  #pragma unroll
  for (int r = 0; r < CRB; ++r)
    #pragma unroll
    for (int j = 0; j < CPW; ++j) acc[r][j] = 0.f;

  __syncthreads();

  for (int ci = 0; ci < 64; ++ci) {
    float wa = w0[ci * 3], wb = w0[ci * 3 + 1], wc = w0[ci * 3 + 2];
    float sc = sb0[2 * ci], bi = sb0[2 * ci + 1];
    __syncthreads();
    for (int li = tid; li < 896; li += 256) {
      int ir = li >> 7, cc = li & 127;
      float v = xtile[ir * ITW + cc] * wa;
      v = fmaf(xtile[(7 + ir) * ITW + cc],  wb, v);
      v = fmaf(xtile[(14 + ir) * ITW + cc], wc, v);
      itile[ir * ITW + cc] = fmaxf(fmaf(v, sc, bi), 0.f);
    }
    if (tid < 144)
      wtile[tid] = w1[((cog * 16 + tid / 9) * 64 + ci) * 9 + (tid % 9)];
    __syncthreads();

    float wr[9];
    #pragma unroll
    for (int k = 0; k < 9; ++k) wr[k] = wtile[co * 9 + k];

    #pragma unroll
    for (int ir = 0; ir < INROWS; ++ir) {
      float seg[12];
      const float4* sp = (const float4*)&itile[ir * ITW + c0];
      *(float4*)&seg[0] = sp[0];
      *(float4*)&seg[4] = sp[1];
      *(float4*)&seg[8] = sp[2];
      #pragma unroll
      for (int dr = 0; dr < 3; ++dr) {
        int r = ir - dr;
        if (r >= 0 && r < CRB) {
          #pragma unroll
          for (int j = 0; j < CPW; ++j) {
            acc[r][j] = fmaf(seg[j + 0], wr[dr * 3 + 0], acc[r][j]);
            acc[r][j] = fmaf(seg[j + 1], wr[dr * 3 + 1], acc[r][j]);
            acc[r][j] = fmaf(seg[j + 2], wr[dr * 3 + 2], acc[r][j]);
          }
        }
      }
    }
  }

  // pool in two 8-channel passes from parea (xtile is dead now)
  #pragma unroll
  for (int half = 0; half < 2; ++half) {
    __syncthreads();
    if ((co >> 3) == half) {
      #pragma unroll
      for (int r = 0; r < CRB; ++r)
        #pragma unroll
        for (int j = 0; j < CPW; ++j)
          parea[((co & 7) * CRB + r) * CTW + c0 + j] = acc[r][j];
    }
    __syncthreads();
    int co2 = tid >> 5, pw2 = tid & 31;
    for (int pr = 0; pr < PRB && pr0 + pr < POOLW; ++pr) {
      for (int pc = pw2; pc < POOLW; pc += 32) {
        float m = -INFINITY;
        #pragma unroll
        for (int dr = 0; dr < 3; ++dr)
          #pragma unroll
          for (int dc = 0; dc < 3; ++dc)
            m = fmaxf(m, parea[(co2 * CRB + 2 * pr + dr) * CTW + 2 * pc + dc]);
        out[((size_t)(b * 64 + cog * 16 + half * 8 + co2) * POOLW + (pr0 + pr))
            * POOLW + pc] = m;
      }
    }
  }
}

// ------- generic: bnrelu(in) -> 3x3 conv -> 3x3/s2 maxpool -------
template<int IN, int POOLW, int PRB, int CPW>
__global__ __launch_bounds__(256) void k_convpool(const float* __restrict__ in,
                                                  const float* __restrict__ w,
                                                  const float* __restrict__ sb,
                                                  float* __restrict__ out) {
  constexpr int CRB    = 2 * PRB + 1;
  constexpr int INROWS = CRB + 2;
  constexpr int ITW    = 16 * CPW + 8;
  constexpr int CTW    = 16 * CPW + 1;
  constexpr int NT     = (POOLW + PRB - 1) / PRB;

  __shared__ __align__(16) float itile[INROWS * ITW];
  __shared__ float wtile[144];
  __shared__ __align__(16) float ctile[8 * CRB * CTW];

  int bid = blockIdx.x;
  int t   = bid % NT;
  int cog = (bid / NT) & 3;
  int b   = bid / (NT * 4);
  int pr0 = t * PRB;
  int tid = threadIdx.x;
  int co  = tid & 15, wkr = tid >> 4, c0 = wkr * CPW;

  float acc[CRB][CPW];
  #pragma unroll
  for (int r = 0; r < CRB; ++r)
    #pragma unroll
    for (int j = 0; j < CPW; ++j) acc[r][j] = 0.f;

  for (int ci = 0; ci < 64; ++ci) {
    const float* ip = in + (size_t)(b * 64 + ci) * (IN * IN);
    float sc = sb[2 * ci], bi = sb[2 * ci + 1];
    __syncthreads();
    for (int li = tid; li < INROWS * IN; li += 256) {
      int ir = li / IN, cc = li - ir * IN;
      int grow = 2 * pr0 + ir;
      float v = 0.f;
      if (grow < IN) v = fmaxf(fmaf(ip[grow * IN + cc], sc, bi), 0.f);
      itile[ir * ITW + cc] = v;
    }
    if (tid < 144)
      wtile[tid] = w[((cog * 16 + tid / 9) * 64 + ci) * 9 + (tid % 9)];
    __syncthreads();

    float wr[9];
    #pragma unroll
    for (int k = 0; k < 9; ++k) wr[k] = wtile[co * 9 + k];

    #pragma unroll
    for (int ir = 0; ir < INROWS; ++ir) {
      float seg[CPW + 6];
      if constexpr (CPW == 4) {
        const float4* sp = (const float4*)&itile[ir * ITW + c0];
        *(float4*)&seg[0] = sp[0];
        *(float4*)&seg[4] = sp[1];
      } else if constexpr (CPW == 2) {
        const float2* sp = (const float2*)&itile[ir * ITW + c0];
        *(float2*)&seg[0] = sp[0];
        *(float2*)&seg[2] = sp[1];
      } else {
        #pragma unroll
        for (int j = 0; j < CPW + 2; ++j) seg[j] = itile[ir * ITW + c0 + j];
      }
      #pragma unroll
      for (int dr = 0; dr < 3; ++dr) {
        int r = ir - dr;
        if (r >= 0 && r < CRB) {
          #pragma unroll
          for (int j = 0; j < CPW; ++j) {
            acc[r][j] = fmaf(seg[j + 0], wr[dr * 3 + 0], acc[r][j]);
            acc[r][j] = fmaf(seg[j + 1], wr[dr * 3 + 1], acc[r][j]);
            acc[r][j] = fmaf(seg[j + 2], wr[dr * 3 + 2], acc[r][j]);
          }
        }
      }
    }
  }

  #pragma unroll
  for (int half = 0; half < 2; ++half) {
    __syncthreads();
    if ((co >> 3) == half) {
      #pragma unroll
      for (int r = 0; r < CRB; ++r)
        #pragma unroll
        for (int j = 0; j < CPW; ++j)
          ctile[((co & 7) * CRB + r) * CTW + c0 + j] = acc[r][j];
    }
    __syncthreads();
    int co2 = tid >> 5, pw2 = tid & 31;
    for (int pr = 0; pr < PRB && pr0 + pr < POOLW; ++pr) {
      for (int pc = pw2; pc < POOLW; pc += 32) {
        float m = -INFINITY;
        #pragma unroll
        for (int dr = 0; dr < 3; ++dr)
          #pragma unroll
          for (int dc = 0; dc < 3; ++dc)
            m = fmaxf(m, ctile[(co2 * CRB + 2 * pr + dr) * CTW + 2 * pc + dc]);
        out[((size_t)(b * 64 + cog * 16 + half * 8 + co2) * POOLW + (pr0 + pr))
            * POOLW + pc] = m;
      }
    }
  }
}

// ---------------- theta = bnrelu(h3_flat) @ W_reg.T + b_reg ----------------
__global__ __launch_bounds__(256) void k_theta(const float* __restrict__ h3,
                                               const float* __restrict__ sb3,
                                               const float* __restrict__ Wreg,
                                               const float* __restrict__ breg,
                                               float* __restrict__ theta_raw) {
  int b = blockIdx.x, tid = threadIdx.x;
  float acc[6] = {0.f, 0.f, 0.f, 0.f, 0.f, 0.f};
  const float* hb = h3 + (size_t)b * 10816;
  for (int i = tid; i < 10816; i += 256) {
    int c = i / 169;
    float f = fmaxf(fmaf(hb[i], sb3[2 * c], sb3[2 * c + 1]), 0.f);
    #pragma unroll
    for (int j = 0; j < 6; ++j) acc[j] += f * Wreg[j * 10816 + i];
  }
  __shared__ float red[6][256];
  #pragma unroll
  for (int j = 0; j < 6; ++j) red[j][tid] = acc[j];
  __syncthreads();
  for (int s = 128; s > 0; s >>= 1) {
    if (tid < s) {
      #pragma unroll
      for (int j = 0; j < 6; ++j) red[j][tid] += red[j][tid + s];
    }
    __syncthreads();
  }
  if (tid < 6) theta_raw[b * 6 + tid] = red[tid][0] + breg[tid];
}

// ---------------- sequential spectral normalization scan ----------------
__global__ void k_spectral(const float* __restrict__ theta_raw,
                           const float* __restrict__ u0v,
                           const float* __restrict__ v0v,
                           float* __restrict__ theta) {
  if (threadIdx.x != 0 || blockIdx.x != 0) return;
  float ua = u0v[0], ub = u0v[1];
  float va = v0v[0], vb = v0v[1], vc = v0v[2];
  for (int n = 0; n < 32; ++n) {
    float W[6];
    #pragma unroll
    for (int k = 0; k < 6; ++k) W[k] = theta_raw[n * 6 + k];
    #pragma unroll
    for (int it = 0; it < 4; ++it) {
      float t0 = W[0]*ua + W[3]*ub;
      float t1 = W[1]*ua + W[4]*ub;
      float t2 = W[2]*ua + W[5]*ub;
      float nv = fmaxf(sqrtf(t0*t0 + t1*t1 + t2*t2), 1e-12f);
      va = t0/nv; vb = t1/nv; vc = t2/nv;
      float s0 = W[0]*va + W[1]*vb + W[2]*vc;
      float s1 = W[3]*va + W[4]*vb + W[5]*vc;
      float nu = fmaxf(sqrtf(s0*s0 + s1*s1), 1e-12f);
      ua = s0/nu; ub = s1/nu;
    }
    float s0 = W[0]*va + W[1]*vb + W[2]*vc;
    float s1 = W[3]*va + W[4]*vb + W[5]*vc;
    float sigma = ua*s0 + ub*s1;
    #pragma unroll
    for (int k = 0; k < 6; ++k) theta[n * 6 + k] = W[k] / sigma;
  }
}

// ---------------- affine grid + reflection bilinear sample ----------------
__global__ __launch_bounds__(256) void k_sample(const float* __restrict__ x,
                                                const float* __restrict__ theta,
                                                float* __restrict__ out) {
  int idx = blockIdx.x * 256 + threadIdx.x;
  int b = idx >> 14, p = idx & 16383;
  int hh = p >> 7, ww = p & 127;
  const float* th = theta + b * 6;
  float xs = (2*ww + 1) * (1.f/128.f) - 1.f;
  float ys = (2*hh + 1) * (1.f/128.f) - 1.f;
  float gx = th[0]*xs + th[1]*ys + th[2];
  float gy = th[3]*xs + th[4]*ys + th[5];
  float ix = ((gx + 1.f) * 128.f - 1.f) * 0.5f;
  float iy = ((gy + 1.f) * 128.f - 1.f) * 0.5f;

  float r;
  r  = fmodf(fabsf(ix + 0.5f), 256.f);
  ix = ((r > 128.f) ? 256.f - r : r) - 0.5f;
  ix = fminf(fmaxf(ix, 0.f), 127.f);
  r  = fmodf(fabsf(iy + 0.5f), 256.f);
  iy = ((r > 128.f) ? 256.f - r : r) - 0.5f;
  iy = fminf(fmaxf(iy, 0.f), 127.f);

  float x0f = floorf(ix), y0f = floorf(iy);
  float wx = ix - x0f, wy = iy - y0f;
  int x0 = (int)x0f; x0 = min(max(x0, 0), 127); int x1 = min(x0 + 1, 127);
  int y0 = (int)y0f; y0 = min(max(y0, 0), 127); int y1 = min(y0 + 1, 127);
  float w00 = (1.f-wx)*(1.f-wy), w10 = wx*(1.f-wy);
  float w01 = (1.f-wx)*wy,       w11 = wx*wy;

  #pragma unroll
  for (int ch = 0; ch < 3; ++ch) {
    const float* xb = x + ((size_t)(b*3 + ch)) * 16384;
    float v = xb[y0*128 + x0]*w00 + xb[y0*128 + x1]*w10
            + xb[y1*128 + x0]*w01 + xb[y1*128 + x1]*w11;
    out[((size_t)(b*3 + ch)) * 16384 + p] = v;
  }
}

__global__ void k_zero(float* p, int n) {
  int i = blockIdx.x * 256 + threadIdx.x;
  if (i < n) p[i] = 0.f;
}

extern "C" void kernel_launch(void* const* d_in, const int* in_sizes, int n_in,
                              void* d_out, int out_size, void* d_ws, size_t ws_size,
                              hipStream_t stream) {
  const float* x     = (const float*)d_in[0];
  const float* w0    = (const float*)d_in[1];
  const float* w1    = (const float*)d_in[2];
  const float* w2    = (const float*)d_in[3];
  const float* w3    = (const float*)d_in[4];
  const float* gamma = (const float*)d_in[5];
  const float* beta  = (const float*)d_in[6];
  const float* Wreg  = (const float*)d_in[7];
  const float* breg  = (const float*)d_in[8];
  const float* u0v   = (const float*)d_in[9];
  const float* v0v   = (const float*)d_in[10];
  float* out = (float*)d_out;

  float* ws   = (float*)d_ws;
  float* h1   = ws;                    // 7,872,512
  float* h2   = h1 + 7872512;          // 1,722,368
  float* h3   = h2 + 1722368;          //   346,112
  float* st   = h3 + 346112;           // 384 (3 layers x 64 x 2)
  float* xst  = st + 384;              // 16
  float* sb0  = xst + 16;              // 128
  float* sbL  = sb0 + 128;             // 384
  float* traw = sbL + 384;             // 192
  float* tfin = traw + 192;            // 192

  k_zero<<<2, 256, 0, stream>>>(st, 400);                 // st + xst
  k_xstats<<<1024, 256, 0, stream>>>(x, xst);
  k_bn0<<<1, 64, 0, stream>>>(xst, w0, gamma, beta, sb0);

  k_convpool1<<<32 * 4 * 31, 256, 0, stream>>>(x, w0, w1, sb0, h1);

  k_stats<<<2048, 256, 0, stream>>>(h1, st, 3844);
  k_finalize<<<1, 64, 0, stream>>>(st, gamma, beta, sbL, 1, 1.f / 123008.f);
  k_convpool<62, 29, 2, 4><<<32 * 4 * 15, 256, 0, stream>>>(h1, w2, sbL, h2);

  k_stats<<<2048, 256, 0, stream>>>(h2, st + 128, 841);
  k_finalize<<<1, 64, 0, stream>>>(st + 128, gamma, beta, sbL + 128, 2, 1.f / 26912.f);
  k_convpool<29, 13, 4, 2><<<32 * 4 * 4, 256, 0, stream>>>(h2, w3, sbL + 128, h3);

  k_stats<<<2048, 256, 0, stream>>>(h3, st + 256, 169);
  k_finalize<<<1, 64, 0, stream>>>(st + 256, gamma, beta, sbL + 256, 3, 1.f / 5408.f);

  k_theta<<<32, 256, 0, stream>>>(h3, sbL + 256, Wreg, breg, traw);
  k_spectral<<<1, 64, 0, stream>>>(traw, u0v, v0v, tfin);
  k_sample<<<2048, 256, 0, stream>>>(x, tfin, out);
}

// Round 4
// 754.987 us; speedup vs baseline: 1.8147x; 1.6365x over previous
//
#include <hip/hip_runtime.h>
#include <math.h>

// B=32, C_IN=3, H=W=128, MID=64
// conv1 now runs on matrix cores: fp16 2-way split (hi + lo*2^11), 3 MFMA
// products per logical tile => ~fp32 precision at ~1/3 of the 2 PF f16 rate.
// Layer structured as 9 shifted K=64 GEMMs (no im2col), input tile staged in
// LDS as split-fp16, weights pre-transposed into A-fragment order by k_wprep.

typedef _Float16 half8_t __attribute__((ext_vector_type(8)));
typedef float f32x4 __attribute__((ext_vector_type(4)));

__device__ inline unsigned short f16bits(_Float16 h) {
  union { _Float16 h; unsigned short u; } cv; cv.h = h; return cv.u;
}

// ---------------- x channel stats (for analytic BN0) ----------------
__global__ __launch_bounds__(256) void k_xstats(const float* __restrict__ x,
                                                float* __restrict__ xst) {
  int g0 = blockIdx.x * 256 + threadIdx.x;
  float a[9] = {0,0,0,0,0,0,0,0,0};
  for (int g = g0; g < 524288; g += 1024 * 256) {
    int b = g >> 14, p = g & 16383;
    const float* xb = x + (size_t)b * 49152 + p;
    float x0 = xb[0], x1 = xb[16384], x2 = xb[32768];
    a[0] += x0; a[1] += x1; a[2] += x2;
    a[3] += x0 * x0; a[4] += x0 * x1; a[5] += x0 * x2;
    a[6] += x1 * x1; a[7] += x1 * x2; a[8] += x2 * x2;
  }
  __shared__ float red[256];
  for (int k = 0; k < 9; ++k) {
    red[threadIdx.x] = a[k];
    __syncthreads();
    for (int s = 128; s > 0; s >>= 1) {
      if (threadIdx.x < s) red[threadIdx.x] += red[threadIdx.x + s];
      __syncthreads();
    }
    if (threadIdx.x == 0) atomicAdd(&xst[k], red[0]);
    __syncthreads();
  }
}

__global__ void k_bn0(const float* __restrict__ xst, const float* __restrict__ w0,
                      const float* __restrict__ gamma, const float* __restrict__ beta,
                      float* __restrict__ sb0) {
  int c = threadIdx.x;
  if (c >= 64) return;
  const float invN = 1.f / 524288.f;
  float mu0 = xst[0] * invN, mu1 = xst[1] * invN, mu2 = xst[2] * invN;
  float M00 = xst[3] * invN, M01 = xst[4] * invN, M02 = xst[5] * invN;
  float M11 = xst[6] * invN, M12 = xst[7] * invN, M22 = xst[8] * invN;
  float wa = w0[c * 3], wb = w0[c * 3 + 1], wc = w0[c * 3 + 2];
  float m  = wa * mu0 + wb * mu1 + wc * mu2;
  float e2 = wa * wa * M00 + wb * wb * M11 + wc * wc * M22
           + 2.f * (wa * wb * M01 + wa * wc * M02 + wb * wc * M12);
  float var = e2 - m * m;
  float sc = gamma[c] / sqrtf(var + 1e-5f);
  sb0[2 * c] = sc;
  sb0[2 * c + 1] = beta[c] - m * sc;
}

// ------- weight prep: W1[co][ci][kh][kw] -> A-fragment order, fp16 split -------
// Wp fp16 idx = (((s*2+p)*8 + (ci>>3))*64 + co)*8 + (ci&7); p=0 hi, p=1 lo*2^11
__global__ __launch_bounds__(256) void k_wprep(const float* __restrict__ w1,
                                               _Float16* __restrict__ Wp) {
  int i = blockIdx.x * 256 + threadIdx.x;   // 9*64*64 = 36864
  if (i >= 36864) return;
  int s = i >> 12, rem = i & 4095;
  int ci = rem >> 6, co = rem & 63;
  float w = w1[(co * 64 + ci) * 9 + s];
  _Float16 hi = (_Float16)w;
  _Float16 lo = (_Float16)((w - (float)hi) * 2048.0f);
  int g = ci >> 3, e = ci & 7;
  Wp[(((size_t)(s * 2 + 0) * 8 + g) * 64 + co) * 8 + e] = hi;
  Wp[(((size_t)(s * 2 + 1) * 8 + g) * 64 + co) * 8 + e] = lo;
}

// ------- layer1 on MFMA: bnrelu(w0.x) staged as split-fp16 -> 9-shift GEMM -> pool
// block: (b, pooled row pr, col half cb). 4 waves, wave = 16 conv cols.
// conv tile: 3 rows x 64 cols x 64 co; input tile 5 rows x 66 cols x ci-chunk 32.
__global__ __launch_bounds__(256) void k_conv1_mfma(
    const float* __restrict__ x, const float* __restrict__ w0,
    const _Float16* __restrict__ Wp, const float* __restrict__ sb0,
    float* __restrict__ out) {
  // input tile: pos = ir*66+ic, stride 144 B = [split0 32ci][split1 32ci][pad16]
  // x_lds (3ch x 330 pos fp32) at byte 47520; pool ctile aliases everything.
  __shared__ __align__(16) unsigned char smem[51488];
  float* x_lds = (float*)(smem + 47520);

  int bid = blockIdx.x;
  int cb = bid & 1, pr = (bid >> 1) % 62, b = (bid >> 1) / 62;
  int CB = cb * 62;
  int t = threadIdx.x;
  int lane = t & 63, wv = t >> 6;
  int cwv = wv * 16;
  int l15 = lane & 15, l4 = lane >> 4;

  for (int i = t; i < 990; i += 256) {
    int ch = i / 330, pos = i - ch * 330;
    int ir = pos / 66, ic = pos - ir * 66;
    x_lds[ch * 330 + pos] =
        x[((size_t)(b * 3 + ch) << 14) + (2 * pr + ir) * 128 + CB + ic];
  }

  f32x4 acc1[3][4], acc2[3][4];
  #pragma unroll
  for (int r = 0; r < 3; ++r)
    #pragma unroll
    for (int ct = 0; ct < 4; ++ct) {
      acc1[r][ct] = (f32x4)0.f;
      acc2[r][ct] = (f32x4)0.f;
    }

  int pair = t & 15;
  int posb = t >> 4;
  int LB = l15 * 144 + l4 * 16;

  for (int q = 0; q < 2; ++q) {
    int ci0 = q * 32 + 2 * pair, ci1 = ci0 + 1;
    float w00 = w0[ci0*3], w01 = w0[ci0*3+1], w02 = w0[ci0*3+2];
    float w10 = w0[ci1*3], w11 = w0[ci1*3+1], w12 = w0[ci1*3+2];
    float sc0 = sb0[2*ci0], bi0 = sb0[2*ci0+1];
    float sc1 = sb0[2*ci1], bi1 = sb0[2*ci1+1];
    __syncthreads();   // x_lds ready (q=0) / prev chunk's B-reads done (q=1)
    for (int pos = posb; pos < 330; pos += 16) {
      float x0 = x_lds[pos], x1 = x_lds[330 + pos], x2 = x_lds[660 + pos];
      float v0 = fmaxf(fmaf(fmaf(x2, w02, fmaf(x1, w01, x0 * w00)), sc0, bi0), 0.f);
      float v1 = fmaxf(fmaf(fmaf(x2, w12, fmaf(x1, w11, x0 * w10)), sc1, bi1), 0.f);
      _Float16 h0 = (_Float16)v0, h1 = (_Float16)v1;
      _Float16 g0 = (_Float16)((v0 - (float)h0) * 2048.f);
      _Float16 g1 = (_Float16)((v1 - (float)h1) * 2048.f);
      unsigned uh = f16bits(h0) | ((unsigned)f16bits(h1) << 16);
      unsigned ul = f16bits(g0) | ((unsigned)f16bits(g1) << 16);
      int base = pos * 144 + pair * 4;
      *(unsigned*)(smem + base) = uh;
      *(unsigned*)(smem + base + 64) = ul;
    }
    __syncthreads();

    #pragma unroll
    for (int s = 0; s < 9; ++s) {
      const int kh = s / 3, kw = s % 3;
      half8_t Ah[4], Al[4];
      #pragma unroll
      for (int ct = 0; ct < 4; ++ct) {
        Ah[ct] = *(const half8_t*)(Wp + ((size_t)((s*2+0)*8 + q*4 + l4) * 64 + ct*16 + l15) * 8);
        Al[ct] = *(const half8_t*)(Wp + ((size_t)((s*2+1)*8 + q*4 + l4) * 64 + ct*16 + l15) * 8);
      }
      #pragma unroll
      for (int r = 0; r < 3; ++r) {
        int rowoff = ((r + kh) * 66 + cwv + kw) * 144 + LB;
        half8_t Bh = *(const half8_t*)(smem + rowoff);
        half8_t Bl = *(const half8_t*)(smem + rowoff + 64);
        #pragma unroll
        for (int ct = 0; ct < 4; ++ct) {
          acc1[r][ct] = __builtin_amdgcn_mfma_f32_16x16x32_f16(Ah[ct], Bh, acc1[r][ct], 0, 0, 0);
          acc2[r][ct] = __builtin_amdgcn_mfma_f32_16x16x32_f16(Ah[ct], Bl, acc2[r][ct], 0, 0, 0);
          acc2[r][ct] = __builtin_amdgcn_mfma_f32_16x16x32_f16(Al[ct], Bh, acc2[r][ct], 0, 0, 0);
        }
      }
    }
  }

  // epilogue: combine splits, dump to ctile [64 co][3 r][65 col], pool 3x3/s2
  __syncthreads();
  float* ctile = (float*)smem;
  #pragma unroll
  for (int r = 0; r < 3; ++r)
    #pragma unroll
    for (int ct = 0; ct < 4; ++ct)
      #pragma unroll
      for (int e = 0; e < 4; ++e) {
        int co = ct * 16 + l4 * 4 + e;
        ctile[(co * 3 + r) * 65 + cwv + l15] =
            acc1[r][ct][e] + acc2[r][ct][e] * (1.f / 2048.f);
      }
  __syncthreads();
  for (int i = t; i < 64 * 31; i += 256) {
    int co = i / 31, pcl = i - co * 31;
    float m = -INFINITY;
    #pragma unroll
    for (int dr = 0; dr < 3; ++dr)
      #pragma unroll
      for (int dc = 0; dc < 3; ++dc)
        m = fmaxf(m, ctile[(co * 3 + dr) * 65 + 2 * pcl + dc]);
    out[((size_t)(b * 64 + co) * 62 + pr) * 62 + cb * 31 + pcl] = m;
  }
}

// ---------------- per-channel sum/sumsq over (B,HW) ----------------
__global__ __launch_bounds__(256) void k_stats(const float* __restrict__ h,
                                               float* __restrict__ st, int S) {
  int c = blockIdx.x & 63, b = blockIdx.x >> 6;
  const float* base = h + (size_t)(b * 64 + c) * S;
  float s = 0.f, s2 = 0.f;
  for (int i = threadIdx.x; i < S; i += 256) {
    float v = base[i]; s += v; s2 += v * v;
  }
  __shared__ float r1[256], r2[256];
  r1[threadIdx.x] = s; r2[threadIdx.x] = s2;
  __syncthreads();
  for (int str = 128; str > 0; str >>= 1) {
    if (threadIdx.x < str) {
      r1[threadIdx.x] += r1[threadIdx.x + str];
      r2[threadIdx.x] += r2[threadIdx.x + str];
    }
    __syncthreads();
  }
  if (threadIdx.x == 0) {
    atomicAdd(&st[2 * c],     r1[0]);
    atomicAdd(&st[2 * c + 1], r2[0]);
  }
}

__global__ void k_finalize(const float* __restrict__ st,
                           const float* __restrict__ gamma,
                           const float* __restrict__ beta,
                           float* __restrict__ sb, int layer, float invN) {
  int t = threadIdx.x;
  if (t >= 64) return;
  float m   = st[2 * t] * invN;
  float var = st[2 * t + 1] * invN - m * m;
  float sc  = gamma[layer * 64 + t] / sqrtf(var + 1e-5f);
  sb[2 * t]     = sc;
  sb[2 * t + 1] = beta[layer * 64 + t] - m * sc;
}

// ------- generic fp32: bnrelu(in) -> 3x3 conv -> 3x3/s2 maxpool (layers 2,3) -------
template<int IN, int POOLW, int PRB, int CPW>
__global__ __launch_bounds__(256) void k_convpool(const float* __restrict__ in,
                                                  const float* __restrict__ w,
                                                  const float* __restrict__ sb,
                                                  float* __restrict__ out) {
  constexpr int CRB    = 2 * PRB + 1;
  constexpr int INROWS = CRB + 2;
  constexpr int ITW    = 16 * CPW + 8;
  constexpr int CTW    = 16 * CPW + 1;
  constexpr int NT     = (POOLW + PRB - 1) / PRB;

  __shared__ __align__(16) float itile[INROWS * ITW];
  __shared__ float wtile[144];
  __shared__ __align__(16) float ctile[8 * CRB * CTW];

  int bid = blockIdx.x;
  int t   = bid % NT;
  int cog = (bid / NT) & 3;
  int b   = bid / (NT * 4);
  int pr0 = t * PRB;
  int tid = threadIdx.x;
  int co  = tid & 15, wkr = tid >> 4, c0 = wkr * CPW;

  float acc[CRB][CPW];
  #pragma unroll
  for (int r = 0; r < CRB; ++r)
    #pragma unroll
    for (int j = 0; j < CPW; ++j) acc[r][j] = 0.f;

  for (int ci = 0; ci < 64; ++ci) {
    const float* ip = in + (size_t)(b * 64 + ci) * (IN * IN);
    float sc = sb[2 * ci], bi = sb[2 * ci + 1];
    __syncthreads();
    for (int li = tid; li < INROWS * IN; li += 256) {
      int ir = li / IN, cc = li - ir * IN;
      int grow = 2 * pr0 + ir;
      float v = 0.f;
      if (grow < IN) v = fmaxf(fmaf(ip[grow * IN + cc], sc, bi), 0.f);
      itile[ir * ITW + cc] = v;
    }
    if (tid < 144)
      wtile[tid] = w[((cog * 16 + tid / 9) * 64 + ci) * 9 + (tid % 9)];
    __syncthreads();

    float wr[9];
    #pragma unroll
    for (int k = 0; k < 9; ++k) wr[k] = wtile[co * 9 + k];

    #pragma unroll
    for (int ir = 0; ir < INROWS; ++ir) {
      float seg[CPW + 6];
      if constexpr (CPW == 4) {
        const float4* sp = (const float4*)&itile[ir * ITW + c0];
        *(float4*)&seg[0] = sp[0];
        *(float4*)&seg[4] = sp[1];
      } else if constexpr (CPW == 2) {
        const float2* sp = (const float2*)&itile[ir * ITW + c0];
        *(float2*)&seg[0] = sp[0];
        *(float2*)&seg[2] = sp[1];
      } else {
        #pragma unroll
        for (int j = 0; j < CPW + 2; ++j) seg[j] = itile[ir * ITW + c0 + j];
      }
      #pragma unroll
      for (int dr = 0; dr < 3; ++dr) {
        int r = ir - dr;
        if (r >= 0 && r < CRB) {
          #pragma unroll
          for (int j = 0; j < CPW; ++j) {
            acc[r][j] = fmaf(seg[j + 0], wr[dr * 3 + 0], acc[r][j]);
            acc[r][j] = fmaf(seg[j + 1], wr[dr * 3 + 1], acc[r][j]);
            acc[r][j] = fmaf(seg[j + 2], wr[dr * 3 + 2], acc[r][j]);
          }
        }
      }
    }
  }

  #pragma unroll
  for (int half = 0; half < 2; ++half) {
    __syncthreads();
    if ((co >> 3) == half) {
      #pragma unroll
      for (int r = 0; r < CRB; ++r)
        #pragma unroll
        for (int j = 0; j < CPW; ++j)
          ctile[((co & 7) * CRB + r) * CTW + c0 + j] = acc[r][j];
    }
    __syncthreads();
    int co2 = tid >> 5, pw2 = tid & 31;
    for (int pr = 0; pr < PRB && pr0 + pr < POOLW; ++pr) {
      for (int pc = pw2; pc < POOLW; pc += 32) {
        float m = -INFINITY;
        #pragma unroll
        for (int dr = 0; dr < 3; ++dr)
          #pragma unroll
          for (int dc = 0; dc < 3; ++dc)
            m = fmaxf(m, ctile[(co2 * CRB + 2 * pr + dr) * CTW + 2 * pc + dc]);
        out[((size_t)(b * 64 + cog * 16 + half * 8 + co2) * POOLW + (pr0 + pr))
            * POOLW + pc] = m;
      }
    }
  }
}

// ---------------- theta = bnrelu(h3_flat) @ W_reg.T + b_reg ----------------
__global__ __launch_bounds__(256) void k_theta(const float* __restrict__ h3,
                                               const float* __restrict__ sb3,
                                               const float* __restrict__ Wreg,
                                               const float* __restrict__ breg,
                                               float* __restrict__ theta_raw) {
  int b = blockIdx.x, tid = threadIdx.x;
  float acc[6] = {0.f, 0.f, 0.f, 0.f, 0.f, 0.f};
  const float* hb = h3 + (size_t)b * 10816;
  for (int i = tid; i < 10816; i += 256) {
    int c = i / 169;
    float f = fmaxf(fmaf(hb[i], sb3[2 * c], sb3[2 * c + 1]), 0.f);
    #pragma unroll
    for (int j = 0; j < 6; ++j) acc[j] += f * Wreg[j * 10816 + i];
  }
  __shared__ float red[6][256];
  #pragma unroll
  for (int j = 0; j < 6; ++j) red[j][tid] = acc[j];
  __syncthreads();
  for (int s = 128; s > 0; s >>= 1) {
    if (tid < s) {
      #pragma unroll
      for (int j = 0; j < 6; ++j) red[j][tid] += red[j][tid + s];
    }
    __syncthreads();
  }
  if (tid < 6) theta_raw[b * 6 + tid] = red[tid][0] + breg[tid];
}

// ---------------- sequential spectral normalization scan ----------------
__global__ void k_spectral(const float* __restrict__ theta_raw,
                           const float* __restrict__ u0v,
                           const float* __restrict__ v0v,
                           float* __restrict__ theta) {
  if (threadIdx.x != 0 || blockIdx.x != 0) return;
  float ua = u0v[0], ub = u0v[1];
  float va = v0v[0], vb = v0v[1], vc = v0v[2];
  for (int n = 0; n < 32; ++n) {
    float W[6];
    #pragma unroll
    for (int k = 0; k < 6; ++k) W[k] = theta_raw[n * 6 + k];
    #pragma unroll
    for (int it = 0; it < 4; ++it) {
      float t0 = W[0]*ua + W[3]*ub;
      float t1 = W[1]*ua + W[4]*ub;
      float t2 = W[2]*ua + W[5]*ub;
      float nv = fmaxf(sqrtf(t0*t0 + t1*t1 + t2*t2), 1e-12f);
      va = t0/nv; vb = t1/nv; vc = t2/nv;
      float s0 = W[0]*va + W[1]*vb + W[2]*vc;
      float s1 = W[3]*va + W[4]*vb + W[5]*vc;
      float nu = fmaxf(sqrtf(s0*s0 + s1*s1), 1e-12f);
      ua = s0/nu; ub = s1/nu;
    }
    float s0 = W[0]*va + W[1]*vb + W[2]*vc;
    float s1 = W[3]*va + W[4]*vb + W[5]*vc;
    float sigma = ua*s0 + ub*s1;
    #pragma unroll
    for (int k = 0; k < 6; ++k) theta[n * 6 + k] = W[k] / sigma;
  }
}

// ---------------- affine grid + reflection bilinear sample ----------------
__global__ __launch_bounds__(256) void k_sample(const float* __restrict__ x,
                                                const float* __restrict__ theta,
                                                float* __restrict__ out) {
  int idx = blockIdx.x * 256 + threadIdx.x;
  int b = idx >> 14, p = idx & 16383;
  int hh = p >> 7, ww = p & 127;
  const float* th = theta + b * 6;
  float xs = (2*ww + 1) * (1.f/128.f) - 1.f;
  float ys = (2*hh + 1) * (1.f/128.f) - 1.f;
  float gx = th[0]*xs + th[1]*ys + th[2];
  float gy = th[3]*xs + th[4]*ys + th[5];
  float ix = ((gx + 1.f) * 128.f - 1.f) * 0.5f;
  float iy = ((gy + 1.f) * 128.f - 1.f) * 0.5f;

  float r;
  r  = fmodf(fabsf(ix + 0.5f), 256.f);
  ix = ((r > 128.f) ? 256.f - r : r) - 0.5f;
  ix = fminf(fmaxf(ix, 0.f), 127.f);
  r  = fmodf(fabsf(iy + 0.5f), 256.f);
  iy = ((r > 128.f) ? 256.f - r : r) - 0.5f;
  iy = fminf(fmaxf(iy, 0.f), 127.f);

  float x0f = floorf(ix), y0f = floorf(iy);
  float wx = ix - x0f, wy = iy - y0f;
  int x0 = (int)x0f; x0 = min(max(x0, 0), 127); int x1 = min(x0 + 1, 127);
  int y0 = (int)y0f; y0 = min(max(y0, 0), 127); int y1 = min(y0 + 1, 127);
  float w00 = (1.f-wx)*(1.f-wy), w10 = wx*(1.f-wy);
  float w01 = (1.f-wx)*wy,       w11 = wx*wy;

  #pragma unroll
  for (int ch = 0; ch < 3; ++ch) {
    const float* xb = x + ((size_t)(b*3 + ch)) * 16384;
    float v = xb[y0*128 + x0]*w00 + xb[y0*128 + x1]*w10
            + xb[y1*128 + x0]*w01 + xb[y1*128 + x1]*w11;
    out[((size_t)(b*3 + ch)) * 16384 + p] = v;
  }
}

__global__ void k_zero(float* p, int n) {
  int i = blockIdx.x * 256 + threadIdx.x;
  if (i < n) p[i] = 0.f;
}

extern "C" void kernel_launch(void* const* d_in, const int* in_sizes, int n_in,
                              void* d_out, int out_size, void* d_ws, size_t ws_size,
                              hipStream_t stream) {
  const float* x     = (const float*)d_in[0];
  const float* w0    = (const float*)d_in[1];
  const float* w1    = (const float*)d_in[2];
  const float* w2    = (const float*)d_in[3];
  const float* w3    = (const float*)d_in[4];
  const float* gamma = (const float*)d_in[5];
  const float* beta  = (const float*)d_in[6];
  const float* Wreg  = (const float*)d_in[7];
  const float* breg  = (const float*)d_in[8];
  const float* u0v   = (const float*)d_in[9];
  const float* v0v   = (const float*)d_in[10];
  float* out = (float*)d_out;

  float* ws   = (float*)d_ws;
  float* h1   = ws;                    // 7,872,512
  float* h2   = h1 + 7872512;          // 1,722,368
  float* h3   = h2 + 1722368;          //   346,112
  float* st   = h3 + 346112;           // 384
  float* xst  = st + 384;              // 16
  float* sb0  = xst + 16;              // 128
  float* sbL  = sb0 + 128;             // 384
  float* traw = sbL + 384;             // 192
  float* tfin = traw + 192;            // 192
  _Float16* Wp = (_Float16*)(tfin + 192);   // 73728 fp16 = 36864 floats

  k_zero<<<2, 256, 0, stream>>>(st, 400);
  k_xstats<<<1024, 256, 0, stream>>>(x, xst);
  k_bn0<<<1, 64, 0, stream>>>(xst, w0, gamma, beta, sb0);
  k_wprep<<<144, 256, 0, stream>>>(w1, Wp);

  k_conv1_mfma<<<32 * 62 * 2, 256, 0, stream>>>(x, w0, Wp, sb0, h1);

  k_stats<<<2048, 256, 0, stream>>>(h1, st, 3844);
  k_finalize<<<1, 64, 0, stream>>>(st, gamma, beta, sbL, 1, 1.f / 123008.f);
  k_convpool<62, 29, 2, 4><<<32 * 4 * 15, 256, 0, stream>>>(h1, w2, sbL, h2);

  k_stats<<<2048, 256, 0, stream>>>(h2, st + 128, 841);
  k_finalize<<<1, 64, 0, stream>>>(st + 128, gamma, beta, sbL + 128, 2, 1.f / 26912.f);
  k_convpool<29, 13, 4, 2><<<32 * 4 * 4, 256, 0, stream>>>(h2, w3, sbL + 128, h3);

  k_stats<<<2048, 256, 0, stream>>>(h3, st + 256, 169);
  k_finalize<<<1, 64, 0, stream>>>(st + 256, gamma, beta, sbL + 256, 3, 1.f / 5408.f);

  k_theta<<<32, 256, 0, stream>>>(h3, sbL + 256, Wreg, breg, traw);
  k_spectral<<<1, 64, 0, stream>>>(traw, u0v, v0v, tfin);
  k_sample<<<2048, 256, 0, stream>>>(x, tfin, out);
}

// Round 7
// 587.777 us; speedup vs baseline: 2.3309x; 1.2845x over previous
//
#include <hip/hip_runtime.h>
#include <math.h>

// B=32, C_IN=3, H=W=128, MID=64
// All three 3x3 convs run on matrix cores via fp16 2-way split (hi + lo*2^11):
// 3 MFMA products per logical tile => ~fp32 precision. No im2col: 9 shifted
// K=64 GEMMs per conv, input tile staged in LDS as split-fp16 (pos stride
// 144B = [32ci hi | 32ci lo | 16B pad]); weights pre-transposed by k_wprep.
// NOTE: each Wp buffer is 9*2*8*64*8 = 73728 HALFS (147456 B) — round-6 bug
// was spacing them 36864 halfs apart (units slip), overlapping the layers.

typedef _Float16 half8_t __attribute__((ext_vector_type(8)));
typedef float f32x4 __attribute__((ext_vector_type(4)));

__device__ inline unsigned short f16bits(_Float16 h) {
  union { _Float16 h; unsigned short u; } cv; cv.h = h; return cv.u;
}

// ---------------- x channel stats (for analytic BN0) ----------------
__global__ __launch_bounds__(256) void k_xstats(const float* __restrict__ x,
                                                float* __restrict__ xst) {
  int g0 = blockIdx.x * 256 + threadIdx.x;
  float a[9] = {0,0,0,0,0,0,0,0,0};
  for (int g = g0; g < 524288; g += 1024 * 256) {
    int b = g >> 14, p = g & 16383;
    const float* xb = x + (size_t)b * 49152 + p;
    float x0 = xb[0], x1 = xb[16384], x2 = xb[32768];
    a[0] += x0; a[1] += x1; a[2] += x2;
    a[3] += x0 * x0; a[4] += x0 * x1; a[5] += x0 * x2;
    a[6] += x1 * x1; a[7] += x1 * x2; a[8] += x2 * x2;
  }
  __shared__ float red[256];
  for (int k = 0; k < 9; ++k) {
    red[threadIdx.x] = a[k];
    __syncthreads();
    for (int s = 128; s > 0; s >>= 1) {
      if (threadIdx.x < s) red[threadIdx.x] += red[threadIdx.x + s];
      __syncthreads();
    }
    if (threadIdx.x == 0) atomicAdd(&xst[k], red[0]);
    __syncthreads();
  }
}

__global__ void k_bn0(const float* __restrict__ xst, const float* __restrict__ w0,
                      const float* __restrict__ gamma, const float* __restrict__ beta,
                      float* __restrict__ sb0) {
  int c = threadIdx.x;
  if (c >= 64) return;
  const float invN = 1.f / 524288.f;
  float mu0 = xst[0] * invN, mu1 = xst[1] * invN, mu2 = xst[2] * invN;
  float M00 = xst[3] * invN, M01 = xst[4] * invN, M02 = xst[5] * invN;
  float M11 = xst[6] * invN, M12 = xst[7] * invN, M22 = xst[8] * invN;
  float wa = w0[c * 3], wb = w0[c * 3 + 1], wc = w0[c * 3 + 2];
  float m  = wa * mu0 + wb * mu1 + wc * mu2;
  float e2 = wa * wa * M00 + wb * wb * M11 + wc * wc * M22
           + 2.f * (wa * wb * M01 + wa * wc * M02 + wb * wc * M12);
  float var = e2 - m * m;
  float sc = gamma[c] / sqrtf(var + 1e-5f);
  sb0[2 * c] = sc;
  sb0[2 * c + 1] = beta[c] - m * sc;
}

// ------- weight prep: W[co][ci][kh][kw] -> A-fragment order, fp16 split -------
// Wp fp16 idx = (((s*2+p)*8 + (ci>>3))*64 + co)*8 + (ci&7); p=0 hi, p=1 lo*2^11
__global__ __launch_bounds__(256) void k_wprep(const float* __restrict__ w1,
                                               _Float16* __restrict__ Wp) {
  int i = blockIdx.x * 256 + threadIdx.x;   // 9*64*64 = 36864
  if (i >= 36864) return;
  int s = i >> 12, rem = i & 4095;
  int ci = rem >> 6, co = rem & 63;
  float w = w1[(co * 64 + ci) * 9 + s];
  _Float16 hi = (_Float16)w;
  _Float16 lo = (_Float16)((w - (float)hi) * 2048.0f);
  int g = ci >> 3, e = ci & 7;
  Wp[(((size_t)(s * 2 + 0) * 8 + g) * 64 + co) * 8 + e] = hi;
  Wp[(((size_t)(s * 2 + 1) * 8 + g) * 64 + co) * 8 + e] = lo;
}

// ------- layer1 on MFMA: bnrelu(w0.x) staged as split-fp16 -> 9-shift GEMM -> pool
__global__ __launch_bounds__(256) void k_conv1_mfma(
    const float* __restrict__ x, const float* __restrict__ w0,
    const _Float16* __restrict__ Wp, const float* __restrict__ sb0,
    float* __restrict__ out) {
  __shared__ __align__(16) unsigned char smem[51488];
  float* x_lds = (float*)(smem + 47520);

  int bid = blockIdx.x;
  int cb = bid & 1, pr = (bid >> 1) % 62, b = (bid >> 1) / 62;
  int CB = cb * 62;
  int t = threadIdx.x;
  int lane = t & 63, wv = t >> 6;
  int cwv = wv * 16;
  int l15 = lane & 15, l4 = lane >> 4;

  for (int i = t; i < 990; i += 256) {
    int ch = i / 330, pos = i - ch * 330;
    int ir = pos / 66, ic = pos - ir * 66;
    x_lds[ch * 330 + pos] =
        x[((size_t)(b * 3 + ch) << 14) + (2 * pr + ir) * 128 + CB + ic];
  }

  f32x4 acc1[3][4], acc2[3][4];
  #pragma unroll
  for (int r = 0; r < 3; ++r)
    #pragma unroll
    for (int ct = 0; ct < 4; ++ct) {
      acc1[r][ct] = (f32x4)0.f;
      acc2[r][ct] = (f32x4)0.f;
    }

  int pair = t & 15;
  int posb = t >> 4;
  int LB = l15 * 144 + l4 * 16;

  for (int q = 0; q < 2; ++q) {
    int ci0 = q * 32 + 2 * pair, ci1 = ci0 + 1;
    float w00 = w0[ci0*3], w01 = w0[ci0*3+1], w02 = w0[ci0*3+2];
    float w10 = w0[ci1*3], w11 = w0[ci1*3+1], w12 = w0[ci1*3+2];
    float sc0 = sb0[2*ci0], bi0 = sb0[2*ci0+1];
    float sc1 = sb0[2*ci1], bi1 = sb0[2*ci1+1];
    __syncthreads();
    for (int pos = posb; pos < 330; pos += 16) {
      float x0 = x_lds[pos], x1 = x_lds[330 + pos], x2 = x_lds[660 + pos];
      float v0 = fmaxf(fmaf(fmaf(x2, w02, fmaf(x1, w01, x0 * w00)), sc0, bi0), 0.f);
      float v1 = fmaxf(fmaf(fmaf(x2, w12, fmaf(x1, w11, x0 * w10)), sc1, bi1), 0.f);
      _Float16 h0 = (_Float16)v0, h1 = (_Float16)v1;
      _Float16 g0 = (_Float16)((v0 - (float)h0) * 2048.f);
      _Float16 g1 = (_Float16)((v1 - (float)h1) * 2048.f);
      unsigned uh = f16bits(h0) | ((unsigned)f16bits(h1) << 16);
      unsigned ul = f16bits(g0) | ((unsigned)f16bits(g1) << 16);
      int base = pos * 144 + pair * 4;
      *(unsigned*)(smem + base) = uh;
      *(unsigned*)(smem + base + 64) = ul;
    }
    __syncthreads();

    #pragma unroll
    for (int s = 0; s < 9; ++s) {
      const int kh = s / 3, kw = s % 3;
      half8_t Ah[4], Al[4];
      #pragma unroll
      for (int ct = 0; ct < 4; ++ct) {
        Ah[ct] = *(const half8_t*)(Wp + ((size_t)((s*2+0)*8 + q*4 + l4) * 64 + ct*16 + l15) * 8);
        Al[ct] = *(const half8_t*)(Wp + ((size_t)((s*2+1)*8 + q*4 + l4) * 64 + ct*16 + l15) * 8);
      }
      #pragma unroll
      for (int r = 0; r < 3; ++r) {
        int rowoff = ((r + kh) * 66 + cwv + kw) * 144 + LB;
        half8_t Bh = *(const half8_t*)(smem + rowoff);
        half8_t Bl = *(const half8_t*)(smem + rowoff + 64);
        #pragma unroll
        for (int ct = 0; ct < 4; ++ct) {
          acc1[r][ct] = __builtin_amdgcn_mfma_f32_16x16x32_f16(Ah[ct], Bh, acc1[r][ct], 0, 0, 0);
          acc2[r][ct] = __builtin_amdgcn_mfma_f32_16x16x32_f16(Ah[ct], Bl, acc2[r][ct], 0, 0, 0);
          acc2[r][ct] = __builtin_amdgcn_mfma_f32_16x16x32_f16(Al[ct], Bh, acc2[r][ct], 0, 0, 0);
        }
      }
    }
  }

  __syncthreads();
  float* ctile = (float*)smem;
  #pragma unroll
  for (int r = 0; r < 3; ++r)
    #pragma unroll
    for (int ct = 0; ct < 4; ++ct)
      #pragma unroll
      for (int e = 0; e < 4; ++e) {
        int co = ct * 16 + l4 * 4 + e;
        ctile[(co * 3 + r) * 65 + cwv + l15] =
            acc1[r][ct][e] + acc2[r][ct][e] * (1.f / 2048.f);
      }
  __syncthreads();
  for (int i = t; i < 64 * 31; i += 256) {
    int co = i / 31, pcl = i - co * 31;
    float m = -INFINITY;
    #pragma unroll
    for (int dr = 0; dr < 3; ++dr)
      #pragma unroll
      for (int dc = 0; dc < 3; ++dc)
        m = fmaxf(m, ctile[(co * 3 + dr) * 65 + 2 * pcl + dc]);
    out[((size_t)(b * 64 + co) * 62 + pr) * 62 + cb * 31 + pcl] = m;
  }
}

// ------- layers 2/3 on MFMA: bnrelu(in) staged split-fp16 -> 9-shift GEMM -> pool
// block: (b, pooled row, col-half h of NH). 4 waves = 2 col-groups x 2 co-groups.
template<int IN, int POOLW, int NH>
__global__ __launch_bounds__(256) void k_convpool_mfma(
    const float* __restrict__ in, const _Float16* __restrict__ Wp,
    const float* __restrict__ sb, float* __restrict__ out) {
  __shared__ __align__(16) unsigned char smem[25344];  // stage 24480 / ctile 25344

  int bid = blockIdx.x;
  int h  = (NH == 2) ? (bid & 1) : 0;
  int pw = (NH == 2) ? (bid >> 1) : bid;
  int pr = pw % POOLW;
  int b  = pw / POOLW;
  int CB = h * 30;          // conv-col base; pc0 = h*15 = CB/2
  int t = threadIdx.x;
  int lane = t & 63, wv = t >> 6;
  int l15 = lane & 15, l4 = lane >> 4;
  int wc = wv & 1, wo = wv >> 1;

  f32x4 acc1[3][2], acc2[3][2];
  #pragma unroll
  for (int r = 0; r < 3; ++r)
    #pragma unroll
    for (int c = 0; c < 2; ++c) { acc1[r][c] = (f32x4)0.f; acc2[r][c] = (f32x4)0.f; }

  for (int q = 0; q < 2; ++q) {
    __syncthreads();   // q=1: prior B-reads complete before overwrite
    for (int li = t; li < 5440; li += 256) {
      int ci = li / 170, pos = li - ci * 170;
      int ir = pos / 34, ic = pos - ir * 34;
      int gci = q * 32 + ci;
      int gc = CB + ic;
      float v = 0.f;
      if (gc < IN)
        v = fmaxf(fmaf(in[((size_t)(b * 64 + gci) * IN + 2 * pr + ir) * IN + gc],
                       sb[2 * gci], sb[2 * gci + 1]), 0.f);
      _Float16 hi = (_Float16)v;
      _Float16 lo = (_Float16)((v - (float)hi) * 2048.f);
      int base = pos * 144 + ci * 2;
      *(_Float16*)(smem + base) = hi;
      *(_Float16*)(smem + base + 64) = lo;
    }
    __syncthreads();
    #pragma unroll
    for (int s = 0; s < 9; ++s) {
      const int kh = s / 3, kw = s % 3;
      half8_t Ah[2], Al[2];
      #pragma unroll
      for (int cti = 0; cti < 2; ++cti) {
        int co = (wo * 2 + cti) * 16 + l15;
        Ah[cti] = *(const half8_t*)(Wp + ((size_t)((s*2+0)*8 + q*4 + l4) * 64 + co) * 8);
        Al[cti] = *(const half8_t*)(Wp + ((size_t)((s*2+1)*8 + q*4 + l4) * 64 + co) * 8);
      }
      #pragma unroll
      for (int r = 0; r < 3; ++r) {
        int rowoff = ((r + kh) * 34 + wc * 16 + l15 + kw) * 144 + l4 * 16;
        half8_t Bh = *(const half8_t*)(smem + rowoff);
        half8_t Bl = *(const half8_t*)(smem + rowoff + 64);
        #pragma unroll
        for (int cti = 0; cti < 2; ++cti) {
          acc1[r][cti] = __builtin_amdgcn_mfma_f32_16x16x32_f16(Ah[cti], Bh, acc1[r][cti], 0, 0, 0);
          acc2[r][cti] = __builtin_amdgcn_mfma_f32_16x16x32_f16(Ah[cti], Bl, acc2[r][cti], 0, 0, 0);
          acc2[r][cti] = __builtin_amdgcn_mfma_f32_16x16x32_f16(Al[cti], Bh, acc2[r][cti], 0, 0, 0);
        }
      }
    }
  }

  __syncthreads();
  float* ctile = (float*)smem;   // [64 co][3 r][33]
  #pragma unroll
  for (int r = 0; r < 3; ++r)
    #pragma unroll
    for (int cti = 0; cti < 2; ++cti)
      #pragma unroll
      for (int e = 0; e < 4; ++e) {
        int co = (wo * 2 + cti) * 16 + l4 * 4 + e;
        ctile[(co * 3 + r) * 33 + wc * 16 + l15] =
            acc1[r][cti][e] + acc2[r][cti][e] * (1.f / 2048.f);
      }
  __syncthreads();
  constexpr int NPC = (NH == 1) ? POOLW : 15;
  int pc0 = h * 15;
  for (int i = t; i < 64 * NPC; i += 256) {
    int co = i / NPC, pcl = i - co * NPC;
    int pc = pc0 + pcl;
    if (pc >= POOLW) continue;
    float m = -INFINITY;
    #pragma unroll
    for (int dr = 0; dr < 3; ++dr)
      #pragma unroll
      for (int dc = 0; dc < 3; ++dc)
        m = fmaxf(m, ctile[(co * 3 + dr) * 33 + 2 * pcl + dc]);
    out[((size_t)(b * 64 + co) * POOLW + pr) * POOLW + pc] = m;
  }
}

// ---------------- per-channel sum/sumsq over (B,HW) ----------------
__global__ __launch_bounds__(256) void k_stats(const float* __restrict__ h,
                                               float* __restrict__ st, int S) {
  int c = blockIdx.x & 63, b = blockIdx.x >> 6;
  const float* base = h + (size_t)(b * 64 + c) * S;
  float s = 0.f, s2 = 0.f;
  for (int i = threadIdx.x; i < S; i += 256) {
    float v = base[i]; s += v; s2 += v * v;
  }
  __shared__ float r1[256], r2[256];
  r1[threadIdx.x] = s; r2[threadIdx.x] = s2;
  __syncthreads();
  for (int str = 128; str > 0; str >>= 1) {
    if (threadIdx.x < str) {
      r1[threadIdx.x] += r1[threadIdx.x + str];
      r2[threadIdx.x] += r2[threadIdx.x + str];
    }
    __syncthreads();
  }
  if (threadIdx.x == 0) {
    atomicAdd(&st[2 * c],     r1[0]);
    atomicAdd(&st[2 * c + 1], r2[0]);
  }
}

__global__ void k_finalize(const float* __restrict__ st,
                           const float* __restrict__ gamma,
                           const float* __restrict__ beta,
                           float* __restrict__ sb, int layer, float invN) {
  int t = threadIdx.x;
  if (t >= 64) return;
  float m   = st[2 * t] * invN;
  float var = st[2 * t + 1] * invN - m * m;
  float sc  = gamma[layer * 64 + t] / sqrtf(var + 1e-5f);
  sb[2 * t]     = sc;
  sb[2 * t + 1] = beta[layer * 64 + t] - m * sc;
}

// ---------------- theta = bnrelu(h3_flat) @ W_reg.T + b_reg ----------------
__global__ __launch_bounds__(256) void k_theta(const float* __restrict__ h3,
                                               const float* __restrict__ sb3,
                                               const float* __restrict__ Wreg,
                                               const float* __restrict__ breg,
                                               float* __restrict__ theta_raw) {
  int b = blockIdx.x, tid = threadIdx.x;
  float acc[6] = {0.f, 0.f, 0.f, 0.f, 0.f, 0.f};
  const float* hb = h3 + (size_t)b * 10816;
  for (int i = tid; i < 10816; i += 256) {
    int c = i / 169;
    float f = fmaxf(fmaf(hb[i], sb3[2 * c], sb3[2 * c + 1]), 0.f);
    #pragma unroll
    for (int j = 0; j < 6; ++j) acc[j] += f * Wreg[j * 10816 + i];
  }
  __shared__ float red[6][256];
  #pragma unroll
  for (int j = 0; j < 6; ++j) red[j][tid] = acc[j];
  __syncthreads();
  for (int s = 128; s > 0; s >>= 1) {
    if (tid < s) {
      #pragma unroll
      for (int j = 0; j < 6; ++j) red[j][tid] += red[j][tid + s];
    }
    __syncthreads();
  }
  if (tid < 6) theta_raw[b * 6 + tid] = red[tid][0] + breg[tid];
}

// ---------------- sequential spectral normalization scan ----------------
__global__ void k_spectral(const float* __restrict__ theta_raw,
                           const float* __restrict__ u0v,
                           const float* __restrict__ v0v,
                           float* __restrict__ theta) {
  if (threadIdx.x != 0 || blockIdx.x != 0) return;
  float ua = u0v[0], ub = u0v[1];
  float va = v0v[0], vb = v0v[1], vc = v0v[2];
  for (int n = 0; n < 32; ++n) {
    float W[6];
    #pragma unroll
    for (int k = 0; k < 6; ++k) W[k] = theta_raw[n * 6 + k];
    #pragma unroll
    for (int it = 0; it < 4; ++it) {
      float t0 = W[0]*ua + W[3]*ub;
      float t1 = W[1]*ua + W[4]*ub;
      float t2 = W[2]*ua + W[5]*ub;
      float nv = fmaxf(sqrtf(t0*t0 + t1*t1 + t2*t2), 1e-12f);
      va = t0/nv; vb = t1/nv; vc = t2/nv;
      float s0 = W[0]*va + W[1]*vb + W[2]*vc;
      float s1 = W[3]*va + W[4]*vb + W[5]*vc;
      float nu = fmaxf(sqrtf(s0*s0 + s1*s1), 1e-12f);
      ua = s0/nu; ub = s1/nu;
    }
    float s0 = W[0]*va + W[1]*vb + W[2]*vc;
    float s1 = W[3]*va + W[4]*vb + W[5]*vc;
    float sigma = ua*s0 + ub*s1;
    #pragma unroll
    for (int k = 0; k < 6; ++k) theta[n * 6 + k] = W[k] / sigma;
  }
}

// ---------------- affine grid + reflection bilinear sample ----------------
__global__ __launch_bounds__(256) void k_sample(const float* __restrict__ x,
                                                const float* __restrict__ theta,
                                                float* __restrict__ out) {
  int idx = blockIdx.x * 256 + threadIdx.x;
  int b = idx >> 14, p = idx & 16383;
  int hh = p >> 7, ww = p & 127;
  const float* th = theta + b * 6;
  float xs = (2*ww + 1) * (1.f/128.f) - 1.f;
  float ys = (2*hh + 1) * (1.f/128.f) - 1.f;
  float gx = th[0]*xs + th[1]*ys + th[2];
  float gy = th[3]*xs + th[4]*ys + th[5];
  float ix = ((gx + 1.f) * 128.f - 1.f) * 0.5f;
  float iy = ((gy + 1.f) * 128.f - 1.f) * 0.5f;

  float r;
  r  = fmodf(fabsf(ix + 0.5f), 256.f);
  ix = ((r > 128.f) ? 256.f - r : r) - 0.5f;
  ix = fminf(fmaxf(ix, 0.f), 127.f);
  r  = fmodf(fabsf(iy + 0.5f), 256.f);
  iy = ((r > 128.f) ? 256.f - r : r) - 0.5f;
  iy = fminf(fmaxf(iy, 0.f), 127.f);

  float x0f = floorf(ix), y0f = floorf(iy);
  float wx = ix - x0f, wy = iy - y0f;
  int x0 = (int)x0f; x0 = min(max(x0, 0), 127); int x1 = min(x0 + 1, 127);
  int y0 = (int)y0f; y0 = min(max(y0, 0), 127); int y1 = min(y0 + 1, 127);
  float w00 = (1.f-wx)*(1.f-wy), w10 = wx*(1.f-wy);
  float w01 = (1.f-wx)*wy,       w11 = wx*wy;

  #pragma unroll
  for (int ch = 0; ch < 3; ++ch) {
    const float* xb = x + ((size_t)(b*3 + ch)) * 16384;
    float v = xb[y0*128 + x0]*w00 + xb[y0*128 + x1]*w10
            + xb[y1*128 + x0]*w01 + xb[y1*128 + x1]*w11;
    out[((size_t)(b*3 + ch)) * 16384 + p] = v;
  }
}

__global__ void k_zero(float* p, int n) {
  int i = blockIdx.x * 256 + threadIdx.x;
  if (i < n) p[i] = 0.f;
}

extern "C" void kernel_launch(void* const* d_in, const int* in_sizes, int n_in,
                              void* d_out, int out_size, void* d_ws, size_t ws_size,
                              hipStream_t stream) {
  const float* x     = (const float*)d_in[0];
  const float* w0    = (const float*)d_in[1];
  const float* w1    = (const float*)d_in[2];
  const float* w2    = (const float*)d_in[3];
  const float* w3    = (const float*)d_in[4];
  const float* gamma = (const float*)d_in[5];
  const float* beta  = (const float*)d_in[6];
  const float* Wreg  = (const float*)d_in[7];
  const float* breg  = (const float*)d_in[8];
  const float* u0v   = (const float*)d_in[9];
  const float* v0v   = (const float*)d_in[10];
  float* out = (float*)d_out;

  float* ws   = (float*)d_ws;
  float* h1   = ws;                    // 7,872,512
  float* h2   = h1 + 7872512;          // 1,722,368
  float* h3   = h2 + 1722368;          //   346,112
  float* st   = h3 + 346112;           // 384
  float* xst  = st + 384;              // 16
  float* sb0  = xst + 16;              // 128
  float* sbL  = sb0 + 128;             // 384
  float* traw = sbL + 384;             // 192
  float* tfin = traw + 192;            // 192
  _Float16* Wp1 = (_Float16*)(tfin + 192);  // 73728 HALFS each (147456 B)
  _Float16* Wp2 = Wp1 + 73728;
  _Float16* Wp3 = Wp2 + 73728;

  k_zero<<<2, 256, 0, stream>>>(st, 400);
  k_xstats<<<1024, 256, 0, stream>>>(x, xst);
  k_bn0<<<1, 64, 0, stream>>>(xst, w0, gamma, beta, sb0);
  k_wprep<<<144, 256, 0, stream>>>(w1, Wp1);
  k_wprep<<<144, 256, 0, stream>>>(w2, Wp2);
  k_wprep<<<144, 256, 0, stream>>>(w3, Wp3);

  k_conv1_mfma<<<32 * 62 * 2, 256, 0, stream>>>(x, w0, Wp1, sb0, h1);

  k_stats<<<2048, 256, 0, stream>>>(h1, st, 3844);
  k_finalize<<<1, 64, 0, stream>>>(st, gamma, beta, sbL, 1, 1.f / 123008.f);
  k_convpool_mfma<62, 29, 2><<<32 * 29 * 2, 256, 0, stream>>>(h1, Wp2, sbL, h2);

  k_stats<<<2048, 256, 0, stream>>>(h2, st + 128, 841);
  k_finalize<<<1, 64, 0, stream>>>(st + 128, gamma, beta, sbL + 128, 2, 1.f / 26912.f);
  k_convpool_mfma<29, 13, 1><<<32 * 13, 256, 0, stream>>>(h2, Wp3, sbL + 128, h3);

  k_stats<<<2048, 256, 0, stream>>>(h3, st + 256, 169);
  k_finalize<<<1, 64, 0, stream>>>(st + 256, gamma, beta, sbL + 256, 3, 1.f / 5408.f);

  k_theta<<<32, 256, 0, stream>>>(h3, sbL + 256, Wreg, breg, traw);
  k_spectral<<<1, 64, 0, stream>>>(traw, u0v, v0v, tfin);
  k_sample<<<2048, 256, 0, stream>>>(x, tfin, out);
}